// Round 1
// baseline (88.523 us; speedup 1.0000x reference)
//
#include <hip/hip_runtime.h>
#include <math.h>

// 6-qubit statevector sim, one batch element per thread, state in registers.
// Qubit q occupies bit (5-q) of the amplitude index (q0 = MSB, matches the
// reference's axis order / C-contiguous flatten).

struct cf { float r, i; };

__device__ __forceinline__ cf cmul(cf a, cf b) {
    return { fmaf(a.r, b.r, -a.i * b.i), fmaf(a.r, b.i, a.i * b.r) };
}
// acc + g*v
__device__ __forceinline__ cf cmac(cf acc, cf g, cf v) {
    acc.r = fmaf(g.r, v.r, fmaf(-g.i, v.i, acc.r));
    acc.i = fmaf(g.r, v.i, fmaf(g.i, v.r, acc.i));
    return acc;
}

// Apply 2x2 complex gate to qubit with mask M (compile-time).
template<int M>
__device__ __forceinline__ void apply1q(cf* st, cf g00, cf g01, cf g10, cf g11) {
#pragma unroll
    for (int i = 0; i < 64; ++i) {
        if (i & M) continue;
        cf a = st[i], b = st[i + M];
        cf na = cmul(g00, a); na = cmac(na, g01, b);
        cf nb = cmul(g10, a); nb = cmac(nb, g11, b);
        st[i] = na; st[i + M] = nb;
    }
}

// CNOT control-mask MC, target-mask MT: pure register renaming after unroll.
template<int MC, int MT>
__device__ __forceinline__ void cnot(cf* st) {
#pragma unroll
    for (int i = 0; i < 64; ++i) {
        if ((i & MC) && !(i & MT)) {
            cf tmp = st[i]; st[i] = st[i + MT]; st[i + MT] = tmp;
        }
    }
}

__global__ __launch_bounds__(256, 2) void qsim_kernel(
    const float* __restrict__ x, const float* __restrict__ theta,
    float* __restrict__ out) {
    // ---- per-block: build the 18 fused RZ*RY*RX gate matrices into LDS ----
    __shared__ float gs[18 * 8];
    const int t = threadIdx.x;
    if (t < 18) {
        const float* th = theta + t * 3;   // theta[l][q][0..2], t = l*6+q
        float sx, cx, sy, cy, sz, cz;
        __sincosf(0.5f * th[0], &sx, &cx);
        __sincosf(0.5f * th[1], &sy, &cy);
        __sincosf(0.5f * th[2], &sz, &cz);
        // M = RY * RX
        cf m00 = {  cy * cx,  sy * sx };
        cf m01 = { -sy * cx, -cy * sx };
        cf m10 = {  sy * cx, -cy * sx };
        cf m11 = {  cy * cx, -sy * sx };
        // G = RZ * M : row0 *= e^{-i th2/2}, row1 *= e^{+i th2/2}
        cf e0 = { cz, -sz }, e1 = { cz, sz };
        cf g00 = cmul(e0, m00), g01 = cmul(e0, m01);
        cf g10 = cmul(e1, m10), g11 = cmul(e1, m11);
        float* o = gs + t * 8;
        o[0] = g00.r; o[1] = g00.i; o[2] = g01.r; o[3] = g01.i;
        o[4] = g10.r; o[5] = g10.i; o[6] = g11.r; o[7] = g11.i;
    }
    __syncthreads();

    const int b = blockIdx.x * 256 + t;

    // ---- encoding: angles from x, then tensor-product initial state ----
    const float4* xv = reinterpret_cast<const float4*>(x + (size_t)b * 24);
    cf v0[6], v1[6];
#pragma unroll
    for (int q = 0; q < 6; ++q) {
        float4 xq = xv[q];
        float m = (xq.x + xq.y + xq.z + xq.w) * 0.25f;
        m = fminf(fmaxf(m, -6.0f), 6.0f);
        float a = m * 0.52359877559829887308f;   // pi/6
        float s2, c2, s4, c4;
        __sincosf(0.50f * a, &s2, &c2);
        __sincosf(0.25f * a, &s4, &c4);
        // column of RZ(a/2)*RX(a) applied to |0>
        v0[q] = { c4 * c2, -s4 * c2 };
        v1[q] = { s4 * s2, -c4 * s2 };
    }

    cf st[64];
    st[0] = v0[0]; st[32] = v1[0];
#pragma unroll
    for (int q = 1; q < 6; ++q) {
        const int m = 32 >> q;
#pragma unroll
        for (int i = 0; i < 64; i += 2 * m) {
            st[i + m] = cmul(st[i], v1[q]);   // write high half first
            st[i]     = cmul(st[i], v0[q]);
        }
    }

    // ---- 3 layers: CNOT ring + fused 1q gates ----
#pragma unroll
    for (int l = 0; l < 3; ++l) {
        cnot<32, 16>(st);   // CNOT(0,1)
        cnot<16,  8>(st);   // CNOT(1,2)
        cnot< 8,  4>(st);   // CNOT(2,3)
        cnot< 4,  2>(st);   // CNOT(3,4)
        cnot< 2,  1>(st);   // CNOT(4,5)
        cnot< 1, 32>(st);   // CNOT(5,0)
        const float* g = gs + l * 48;
#define G4(o) cf{g[(o)+0], g[(o)+1]}, cf{g[(o)+2], g[(o)+3]}, \
              cf{g[(o)+4], g[(o)+5]}, cf{g[(o)+6], g[(o)+7]}
        apply1q<32>(st, G4(0));
        apply1q<16>(st, G4(8));
        apply1q< 8>(st, G4(16));
        apply1q< 4>(st, G4(24));
        apply1q< 2>(st, G4(32));
        apply1q< 1>(st, G4(40));
#undef G4
    }

    // ---- measurements: Z0,Z2,Z4 via 8 sign-buckets; X1,X3,X5 via pair sums ----
    float s[8] = {0, 0, 0, 0, 0, 0, 0, 0};
#pragma unroll
    for (int i = 0; i < 64; ++i) {
        float p = fmaf(st[i].r, st[i].r, st[i].i * st[i].i);
        const int gi = (((i >> 5) & 1) << 2) | (((i >> 3) & 1) << 1) | ((i >> 1) & 1);
        s[gi] += p;
    }
    float z0 = (s[0] + s[1] + s[2] + s[3]) - (s[4] + s[5] + s[6] + s[7]);
    float z2 = (s[0] + s[1] + s[4] + s[5]) - (s[2] + s[3] + s[6] + s[7]);
    float z4 = (s[0] + s[2] + s[4] + s[6]) - (s[1] + s[3] + s[5] + s[7]);

    float x1 = 0.0f, x3 = 0.0f, x5 = 0.0f;
#pragma unroll
    for (int i = 0; i < 64; ++i) {
        if (!(i & 16)) x1 = fmaf(st[i].r, st[i + 16].r, fmaf(st[i].i, st[i + 16].i, x1));
        if (!(i &  4)) x3 = fmaf(st[i].r, st[i +  4].r, fmaf(st[i].i, st[i +  4].i, x3));
        if (!(i &  1)) x5 = fmaf(st[i].r, st[i +  1].r, fmaf(st[i].i, st[i +  1].i, x5));
    }
    x1 *= 2.0f; x3 *= 2.0f; x5 *= 2.0f;

    float4* ov = reinterpret_cast<float4*>(out + (size_t)b * 8);
    ov[0] = make_float4(z0, x1, z2, x3);
    ov[1] = make_float4(z4, x5, z0, x1);   // k=6 dups Z0, k=7 dups X1
}

extern "C" void kernel_launch(void* const* d_in, const int* in_sizes, int n_in,
                              void* d_out, int out_size, void* d_ws, size_t ws_size,
                              hipStream_t stream) {
    const float* x     = (const float*)d_in[0];   // [B, 24] f32
    const float* theta = (const float*)d_in[1];   // [3, 6, 3] f32
    float* out = (float*)d_out;                   // [B, 8] f32
    const int B = in_sizes[0] / 24;               // 131072
    qsim_kernel<<<dim3(B / 256), dim3(256), 0, stream>>>(x, theta, out);
}